// Round 3
// baseline (635.453 us; speedup 1.0000x reference)
//
#include <hip/hip_runtime.h>
#include <hip/hip_bf16.h>

#define BB 2
#define SS 2048
#define DD 1024
#define HH 16
#define DKV 64

typedef __attribute__((ext_vector_type(8))) short short8;
typedef __attribute__((ext_vector_type(4))) short short4_t;
typedef __attribute__((ext_vector_type(4))) float f32x4;

#define MFMA16(a, b, c) __builtin_amdgcn_mfma_f32_16x16x32_bf16(a, b, c, 0, 0, 0)

__device__ __forceinline__ short f2bf(float f) {
    __hip_bfloat16 h = __float2bfloat16(f);
    union { __hip_bfloat16 h; short s; } u;
    u.h = h;
    return u.s;
}
__device__ __forceinline__ float bf2f(short s) {
    union { short s; __hip_bfloat16 h; } u;
    u.s = s;
    return __bfloat162float(u.h);
}

// ---------------------------------------------------------------------------
// Mask bit-pack: bits[word] = ballot over 64 consecutive mask ints
// ---------------------------------------------------------------------------
__global__ __launch_bounds__(256) void pack_kernel(
    const int* __restrict__ mask, unsigned long long* __restrict__ bits, int nwords)
{
    const int lane = threadIdx.x & 63;
    int w = blockIdx.x * 4 + (threadIdx.x >> 6);
    const int stride = gridDim.x * 4;
    for (; w < nwords; w += stride) {
        int mv = mask[(size_t)w * 64 + lane];
        unsigned long long bal = __ballot(mv != 0);
        if (lane == 0) bits[w] = bal;
    }
}

// ---------------------------------------------------------------------------
// Fused projection GEMMs (q/k/v). z=0,1 -> head-row-major [b][h][s][64];
// z=2 (V) -> transposed per head: vT[b][h][d][s].
// ---------------------------------------------------------------------------
__global__ __launch_bounds__(256) void proj3_kernel(
    const float* __restrict__ A0, const float* __restrict__ A1, const float* __restrict__ A2,
    const float* __restrict__ W0, const float* __restrict__ W1, const float* __restrict__ W2,
    const float* __restrict__ bq, const float* __restrict__ bk, const float* __restrict__ bv,
    __hip_bfloat16* __restrict__ o0, __hip_bfloat16* __restrict__ o1, __hip_bfloat16* __restrict__ o2)
{
    const int z = blockIdx.z;
    const float* A = (z == 0) ? A0 : (z == 1) ? A1 : A2;
    const float* W = (z == 0) ? W0 : (z == 1) ? W1 : W2;
    const float* bias = (z == 0) ? bq : (z == 1) ? bk : bv;
    __hip_bfloat16* outh = (z == 0) ? o0 : (z == 1) ? o1 : o2;

    __shared__ __align__(16) short As[128][40];
    __shared__ __align__(16) short Bs[128][40];  // transposed: Bs[col][k]
    const int t = threadIdx.x;
    const int lane = t & 63;
    const int wave = t >> 6;
    const int wm = wave >> 1, wn = wave & 1;
    const int m0 = blockIdx.x * 128, n0 = blockIdx.y * 128;
    const int lr = lane & 15;
    const int kb = (lane >> 4) * 8;

    f32x4 acc[4][4] = {};

    for (int k0 = 0; k0 < DD; k0 += 32) {
        __syncthreads();
        {
            const int row = t >> 1, kk = (t & 1) * 16;
            const float* src = A + (size_t)(m0 + row) * DD + k0 + kk;
            float4 fa = *(const float4*)(src);
            float4 fb = *(const float4*)(src + 4);
            float4 fc = *(const float4*)(src + 8);
            float4 fd = *(const float4*)(src + 12);
            short8 v0 = { f2bf(fa.x), f2bf(fa.y), f2bf(fa.z), f2bf(fa.w),
                          f2bf(fb.x), f2bf(fb.y), f2bf(fb.z), f2bf(fb.w) };
            short8 v1 = { f2bf(fc.x), f2bf(fc.y), f2bf(fc.z), f2bf(fc.w),
                          f2bf(fd.x), f2bf(fd.y), f2bf(fd.z), f2bf(fd.w) };
            *(short8*)&As[row][kk]     = v0;
            *(short8*)&As[row][kk + 8] = v1;
        }
        {
            const int kk = t >> 3, c0 = (t & 7) * 16;
            const float* src = W + (size_t)(k0 + kk) * DD + n0 + c0;
            #pragma unroll
            for (int i = 0; i < 16; i += 4) {
                float4 f = *(const float4*)(src + i);
                Bs[c0 + i + 0][kk] = f2bf(f.x);
                Bs[c0 + i + 1][kk] = f2bf(f.y);
                Bs[c0 + i + 2][kk] = f2bf(f.z);
                Bs[c0 + i + 3][kk] = f2bf(f.w);
            }
        }
        __syncthreads();
        short8 af[4], bfr[4];
        #pragma unroll
        for (int i = 0; i < 4; i++) af[i]  = *(const short8*)&As[wm * 64 + i * 16 + lr][kb];
        #pragma unroll
        for (int j = 0; j < 4; j++) bfr[j] = *(const short8*)&Bs[wn * 64 + j * 16 + lr][kb];
        #pragma unroll
        for (int i = 0; i < 4; i++)
            #pragma unroll
            for (int j = 0; j < 4; j++)
                acc[i][j] = MFMA16(af[i], bfr[j], acc[i][j]);
    }

    if (z != 2) {
        #pragma unroll
        for (int j = 0; j < 4; j++) {
            const int col = n0 + wn * 64 + j * 16 + lr;
            const float bvv = bias[col];
            const int h = col >> 6, d = col & 63;
            #pragma unroll
            for (int i = 0; i < 4; i++) {
                #pragma unroll
                for (int r = 0; r < 4; r++) {
                    const int m = m0 + wm * 64 + i * 16 + (lane >> 4) * 4 + r;
                    const int b = m >> 11, s = m & (SS - 1);
                    outh[(((size_t)(b * HH + h)) * SS + s) * DKV + d] =
                        __float2bfloat16(acc[i][j][r] + bvv);
                }
            }
        }
    } else {
        short* vT = (short*)outh;
        #pragma unroll
        for (int j = 0; j < 4; j++) {
            const int col = n0 + wn * 64 + j * 16 + lr;
            const float bvv = bias[col];
            const int h = col >> 6, d = col & 63;
            #pragma unroll
            for (int i = 0; i < 4; i++) {
                const int m = m0 + wm * 64 + i * 16 + (lane >> 4) * 4;
                const int b = m >> 11, s = m & (SS - 1);
                short4_t pk;
                #pragma unroll
                for (int r = 0; r < 4; r++) pk[r] = f2bf(acc[i][j][r] + bvv);
                *(short4_t*)(vT + ((size_t)(b * HH + h) * DKV + d) * SS + s) = pk;
            }
        }
    }
}

// ---------------------------------------------------------------------------
// Output GEMM: out[M,N] (fp32) = ctx[M,K](bf16) @ wo[K,N] + bo + residual
// ---------------------------------------------------------------------------
__global__ __launch_bounds__(256) void outproj_kernel(
    const __hip_bfloat16* __restrict__ Actx, const float* __restrict__ W,
    const float* __restrict__ bias, const float* __restrict__ resid,
    float* __restrict__ out)
{
    __shared__ __align__(16) short As[128][40];
    __shared__ __align__(16) short Bs[128][40];
    const int t = threadIdx.x;
    const int lane = t & 63;
    const int wave = t >> 6;
    const int wm = wave >> 1, wn = wave & 1;
    const int m0 = blockIdx.x * 128, n0 = blockIdx.y * 128;
    const int lr = lane & 15;
    const int kb = (lane >> 4) * 8;

    f32x4 acc[4][4] = {};

    for (int k0 = 0; k0 < DD; k0 += 32) {
        __syncthreads();
        {
            const int row = t >> 1, kk = (t & 1) * 16;
            const short8* src = (const short8*)((const short*)Actx + (size_t)(m0 + row) * DD + k0 + kk);
            *(short8*)&As[row][kk]     = src[0];
            *(short8*)&As[row][kk + 8] = src[1];
        }
        {
            const int kk = t >> 3, c0 = (t & 7) * 16;
            const float* src = W + (size_t)(k0 + kk) * DD + n0 + c0;
            #pragma unroll
            for (int i = 0; i < 16; i += 4) {
                float4 f = *(const float4*)(src + i);
                Bs[c0 + i + 0][kk] = f2bf(f.x);
                Bs[c0 + i + 1][kk] = f2bf(f.y);
                Bs[c0 + i + 2][kk] = f2bf(f.z);
                Bs[c0 + i + 3][kk] = f2bf(f.w);
            }
        }
        __syncthreads();
        short8 af[4], bfr[4];
        #pragma unroll
        for (int i = 0; i < 4; i++) af[i]  = *(const short8*)&As[wm * 64 + i * 16 + lr][kb];
        #pragma unroll
        for (int j = 0; j < 4; j++) bfr[j] = *(const short8*)&Bs[wn * 64 + j * 16 + lr][kb];
        #pragma unroll
        for (int i = 0; i < 4; i++)
            #pragma unroll
            for (int j = 0; j < 4; j++)
                acc[i][j] = MFMA16(af[i], bfr[j], acc[i][j]);
    }

    #pragma unroll
    for (int j = 0; j < 4; j++) {
        const int col = n0 + wn * 64 + j * 16 + lr;
        const float bvv = bias[col];
        #pragma unroll
        for (int i = 0; i < 4; i++) {
            #pragma unroll
            for (int r = 0; r < 4; r++) {
                const int m = m0 + wm * 64 + i * 16 + (lane >> 4) * 4 + r;
                out[(size_t)m * DD + col] = acc[i][j][r] + bvv + resid[(size_t)m * DD + col];
            }
        }
    }
}

// ---------------------------------------------------------------------------
// Attention v2: barrier-free, register-direct fragments.
// Block = 4 waves, each wave owns 16 q-rows; grid = B*H*32 = 1024.
// K & V fragments loaded directly from global (L1/L2-served); V is
// pre-transposed (vT[b][h][d][s]) so PV B-frags are contiguous 16B loads.
// Only LDS use: per-wave Ps redistribution (wave-internal, no barriers).
// ---------------------------------------------------------------------------
__global__ __launch_bounds__(256) void attn_kernel(
    const __hip_bfloat16* __restrict__ qh, const __hip_bfloat16* __restrict__ kh,
    const __hip_bfloat16* __restrict__ vT, const unsigned long long* __restrict__ bits,
    float* __restrict__ attn, __hip_bfloat16* __restrict__ ctx)
{
    __shared__ __align__(16) short Ps[4][16][72];  // per-wave P tile
    const int t = threadIdx.x, lane = t & 63, w = t >> 6;

    // bijective XCD swizzle: 1024 blocks, 8 XCDs, 128 contiguous per XCD
    int bid = blockIdx.x;
    bid = (bid & 7) * 128 + (bid >> 3);
    const int qt = bid & 31;
    const int bh = bid >> 5;
    const int h = bh & (HH - 1);
    const int b = bh >> 4;
    const int q0 = qt * 64 + w * 16;       // this wave's 16 q-rows
    const size_t headbase = ((size_t)(b * HH + h)) * SS * DKV;
    const int lr = lane & 15;
    const int kb = (lane >> 4) * 8;
    const int rbase = (lane >> 4) * 4;

    const short* qbase = (const short*)qh + headbase;
    const short* kbase = (const short*)kh + headbase;
    const short* vbase = (const short*)vT + (size_t)(b * HH + h) * DKV * SS;
    const unsigned long long* mrow = bits + ((size_t)b * SS + q0) * (SS / 64);

    // Q fragments (resident)
    short8 aq0 = *(const short8*)(qbase + (size_t)(q0 + lr) * DKV + kb);
    short8 aq1 = *(const short8*)(qbase + (size_t)(q0 + lr) * DKV + 32 + kb);

    float lsum[4] = {0.f, 0.f, 0.f, 0.f};

    // ---------------- pass 1: row sums ----------------
    for (int kt = 0; kt < 32; ++kt) {
        const int k0 = kt * 64;
        f32x4 sc[4];
        #pragma unroll
        for (int fc = 0; fc < 4; ++fc) {
            const short* kr = kbase + (size_t)(k0 + fc * 16 + lr) * DKV + kb;
            short8 bk0 = *(const short8*)(kr);
            short8 bk1 = *(const short8*)(kr + 32);
            f32x4 s = {0.f, 0.f, 0.f, 0.f};
            s = MFMA16(aq0, bk0, s);
            s = MFMA16(aq1, bk1, s);
            sc[fc] = s;
        }
        unsigned long long mw[4];
        #pragma unroll
        for (int r = 0; r < 4; ++r) mw[r] = mrow[(size_t)(rbase + r) * (SS / 64) + kt];
        #pragma unroll
        for (int fc = 0; fc < 4; ++fc)
            #pragma unroll
            for (int r = 0; r < 4; ++r) {
                const bool masked = (mw[r] >> (fc * 16 + lr)) & 1ull;
                lsum[r] += masked ? 0.f : __expf(sc[fc][r] * 0.125f);
            }
    }
    #pragma unroll
    for (int r = 0; r < 4; r++) {
        float s = lsum[r];
        s += __shfl_xor(s, 1);
        s += __shfl_xor(s, 2);
        s += __shfl_xor(s, 4);
        s += __shfl_xor(s, 8);
        lsum[r] = s;
    }
    float linv[4];
    #pragma unroll
    for (int r = 0; r < 4; r++) linv[r] = 1.f / lsum[r];

    f32x4 cacc[4] = {};
    float* arow = attn + (((size_t)(b * HH + h)) * SS + q0) * SS;

    // ---------------- pass 2: attn write + context ----------------
    for (int kt = 0; kt < 32; ++kt) {
        const int k0 = kt * 64;
        f32x4 sc[4];
        #pragma unroll
        for (int fc = 0; fc < 4; ++fc) {
            const short* kr = kbase + (size_t)(k0 + fc * 16 + lr) * DKV + kb;
            short8 bk0 = *(const short8*)(kr);
            short8 bk1 = *(const short8*)(kr + 32);
            f32x4 s = {0.f, 0.f, 0.f, 0.f};
            s = MFMA16(aq0, bk0, s);
            s = MFMA16(aq1, bk1, s);
            sc[fc] = s;
        }
        unsigned long long mw[4];
        #pragma unroll
        for (int r = 0; r < 4; ++r) mw[r] = mrow[(size_t)(rbase + r) * (SS / 64) + kt];
        #pragma unroll
        for (int fc = 0; fc < 4; ++fc)
            #pragma unroll
            for (int r = 0; r < 4; ++r) {
                const bool masked = (mw[r] >> (fc * 16 + lr)) & 1ull;
                float p = masked ? 0.f : __expf(sc[fc][r] * 0.125f) * linv[r];
                arow[(size_t)(rbase + r) * SS + k0 + fc * 16 + lr] = p;
                Ps[w][rbase + r][fc * 16 + lr] = f2bf(p);
            }
        // wave-internal LDS dependency: compiler inserts lgkmcnt wait
        short8 ap0 = *(const short8*)&Ps[w][lr][kb];
        short8 ap1 = *(const short8*)&Ps[w][lr][32 + kb];
        #pragma unroll
        for (int fd = 0; fd < 4; ++fd) {
            const short* vr = vbase + (size_t)(fd * 16 + lr) * SS + k0 + kb;
            short8 bv0 = *(const short8*)(vr);
            short8 bv1 = *(const short8*)(vr + 32);
            cacc[fd] = MFMA16(ap0, bv0, cacc[fd]);
            cacc[fd] = MFMA16(ap1, bv1, cacc[fd]);
        }
    }

    #pragma unroll
    for (int fd = 0; fd < 4; ++fd)
        #pragma unroll
        for (int r = 0; r < 4; r++) {
            const int qrow = q0 + rbase + r;
            ctx[((size_t)b * SS + qrow) * DD + h * DKV + fd * 16 + lr] =
                __float2bfloat16(cacc[fd][r]);
        }
}

// ---------------------------------------------------------------------------
// LayerNorm in place on out[4096][1024], biased var, eps=1e-5
// ---------------------------------------------------------------------------
__global__ __launch_bounds__(256) void ln_kernel(
    float* __restrict__ io, const float* __restrict__ g, const float* __restrict__ bta)
{
    const int row = blockIdx.x;
    const int t = threadIdx.x;
    float* p = io + (size_t)row * DD;
    float4 x = *(float4*)(p + t * 4);
    float s  = x.x + x.y + x.z + x.w;
    float s2 = x.x * x.x + x.y * x.y + x.z * x.z + x.w * x.w;
    #pragma unroll
    for (int off = 32; off; off >>= 1) {
        s  += __shfl_xor(s, off);
        s2 += __shfl_xor(s2, off);
    }
    __shared__ float as_[4], bs_[4];
    const int w = t >> 6, l = t & 63;
    if (!l) { as_[w] = s; bs_[w] = s2; }
    __syncthreads();
    s  = as_[0] + as_[1] + as_[2] + as_[3];
    s2 = bs_[0] + bs_[1] + bs_[2] + bs_[3];
    const float mu  = s * (1.f / DD);
    const float var = s2 * (1.f / DD) - mu * mu;
    const float rs  = rsqrtf(var + 1e-5f);
    float4 gv = *(const float4*)(g + t * 4);
    float4 bv = *(const float4*)(bta + t * 4);
    float4 o;
    o.x = (x.x - mu) * rs * gv.x + bv.x;
    o.y = (x.y - mu) * rs * gv.y + bv.y;
    o.z = (x.z - mu) * rs * gv.z + bv.z;
    o.w = (x.w - mu) * rs * gv.w + bv.w;
    *(float4*)(p + t * 4) = o;
}

// ---------------------------------------------------------------------------
extern "C" void kernel_launch(void* const* d_in, const int* in_sizes, int n_in,
                              void* d_out, int out_size, void* d_ws, size_t ws_size,
                              hipStream_t stream)
{
    (void)in_sizes; (void)n_in; (void)out_size; (void)ws_size;
    const float* q     = (const float*)d_in[0];
    const float* k     = (const float*)d_in[1];
    const float* v     = (const float*)d_in[2];
    const int*   mask  = (const int*)d_in[3];
    const float* wq    = (const float*)d_in[4];
    const float* bq    = (const float*)d_in[5];
    const float* wk    = (const float*)d_in[6];
    const float* bk    = (const float*)d_in[7];
    const float* wv    = (const float*)d_in[8];
    const float* bv    = (const float*)d_in[9];
    const float* wo    = (const float*)d_in[10];
    const float* bo    = (const float*)d_in[11];
    const float* gamma = (const float*)d_in[12];
    const float* beta  = (const float*)d_in[13];

    float* out  = (float*)d_out;                    // [B,S,D]
    float* attn = out + (size_t)BB * SS * DD;       // [B,H,S,S]

    const size_t hsz = (size_t)BB * HH * SS * DKV;  // 4,194,304
    __hip_bfloat16* qhp = (__hip_bfloat16*)d_ws;
    __hip_bfloat16* khp = qhp + hsz;
    __hip_bfloat16* vTp = khp + hsz;                // vT[b][h][d][s]
    __hip_bfloat16* ctx = vTp + hsz;
    unsigned long long* bits = (unsigned long long*)(ctx + hsz);  // 1 MB

    const int nwords = BB * SS * (SS / 64);  // 131072
    pack_kernel<<<512, 256, 0, stream>>>(mask, bits, nwords);

    dim3 gg(32, 8, 3);
    proj3_kernel<<<gg, 256, 0, stream>>>(q, k, v, wq, wk, wv, bq, bk, bv, qhp, khp, vTp);
    attn_kernel<<<BB * HH * 32, 256, 0, stream>>>(qhp, khp, vTp, bits, attn, ctx);
    dim3 go(32, 8);
    outproj_kernel<<<go, 256, 0, stream>>>(ctx, wo, bo, q, out);
    ln_kernel<<<BB * SS, 256, 0, stream>>>(out, gamma, beta);
}

// Round 4
// 420.866 us; speedup vs baseline: 1.5099x; 1.5099x over previous
//
#include <hip/hip_runtime.h>
#include <hip/hip_bf16.h>

#define BB 2
#define SS 2048
#define DD 1024
#define HH 16
#define DKV 64

typedef __attribute__((ext_vector_type(8))) short short8;
typedef __attribute__((ext_vector_type(4))) short short4_t;
typedef __attribute__((ext_vector_type(4))) float f32x4;

#define MFMA16(a, b, c) __builtin_amdgcn_mfma_f32_16x16x32_bf16(a, b, c, 0, 0, 0)

__device__ __forceinline__ short f2bf(float f) {
    __hip_bfloat16 h = __float2bfloat16(f);
    union { __hip_bfloat16 h; short s; } u;
    u.h = h;
    return u.s;
}

// ---------------------------------------------------------------------------
// Fused projection GEMMs (q/k/v). z=0,1 -> head-row-major [b][h][s][64];
// z=2 (V) -> transposed per head: vT[b][h][d][s].
// ---------------------------------------------------------------------------
__global__ __launch_bounds__(256) void proj3_kernel(
    const float* __restrict__ A0, const float* __restrict__ A1, const float* __restrict__ A2,
    const float* __restrict__ W0, const float* __restrict__ W1, const float* __restrict__ W2,
    const float* __restrict__ bq, const float* __restrict__ bk, const float* __restrict__ bv,
    __hip_bfloat16* __restrict__ o0, __hip_bfloat16* __restrict__ o1, __hip_bfloat16* __restrict__ o2)
{
    const int z = blockIdx.z;
    const float* A = (z == 0) ? A0 : (z == 1) ? A1 : A2;
    const float* W = (z == 0) ? W0 : (z == 1) ? W1 : W2;
    const float* bias = (z == 0) ? bq : (z == 1) ? bk : bv;
    __hip_bfloat16* outh = (z == 0) ? o0 : (z == 1) ? o1 : o2;

    __shared__ __align__(16) short As[128][40];
    __shared__ __align__(16) short Bs[128][40];  // transposed: Bs[col][k]
    const int t = threadIdx.x;
    const int lane = t & 63;
    const int wave = t >> 6;
    const int wm = wave >> 1, wn = wave & 1;
    const int m0 = blockIdx.x * 128, n0 = blockIdx.y * 128;
    const int lr = lane & 15;
    const int kb = (lane >> 4) * 8;

    f32x4 acc[4][4] = {};

    for (int k0 = 0; k0 < DD; k0 += 32) {
        __syncthreads();
        {
            const int row = t >> 1, kk = (t & 1) * 16;
            const float* src = A + (size_t)(m0 + row) * DD + k0 + kk;
            float4 fa = *(const float4*)(src);
            float4 fb = *(const float4*)(src + 4);
            float4 fc = *(const float4*)(src + 8);
            float4 fd = *(const float4*)(src + 12);
            short8 v0 = { f2bf(fa.x), f2bf(fa.y), f2bf(fa.z), f2bf(fa.w),
                          f2bf(fb.x), f2bf(fb.y), f2bf(fb.z), f2bf(fb.w) };
            short8 v1 = { f2bf(fc.x), f2bf(fc.y), f2bf(fc.z), f2bf(fc.w),
                          f2bf(fd.x), f2bf(fd.y), f2bf(fd.z), f2bf(fd.w) };
            *(short8*)&As[row][kk]     = v0;
            *(short8*)&As[row][kk + 8] = v1;
        }
        {
            const int kk = t >> 3, c0 = (t & 7) * 16;
            const float* src = W + (size_t)(k0 + kk) * DD + n0 + c0;
            #pragma unroll
            for (int i = 0; i < 16; i += 4) {
                float4 f = *(const float4*)(src + i);
                Bs[c0 + i + 0][kk] = f2bf(f.x);
                Bs[c0 + i + 1][kk] = f2bf(f.y);
                Bs[c0 + i + 2][kk] = f2bf(f.z);
                Bs[c0 + i + 3][kk] = f2bf(f.w);
            }
        }
        __syncthreads();
        short8 af[4], bfr[4];
        #pragma unroll
        for (int i = 0; i < 4; i++) af[i]  = *(const short8*)&As[wm * 64 + i * 16 + lr][kb];
        #pragma unroll
        for (int j = 0; j < 4; j++) bfr[j] = *(const short8*)&Bs[wn * 64 + j * 16 + lr][kb];
        #pragma unroll
        for (int i = 0; i < 4; i++)
            #pragma unroll
            for (int j = 0; j < 4; j++)
                acc[i][j] = MFMA16(af[i], bfr[j], acc[i][j]);
    }

    if (z != 2) {
        #pragma unroll
        for (int j = 0; j < 4; j++) {
            const int col = n0 + wn * 64 + j * 16 + lr;
            const float bvv = bias[col];
            const int h = col >> 6, d = col & 63;
            #pragma unroll
            for (int i = 0; i < 4; i++) {
                #pragma unroll
                for (int r = 0; r < 4; r++) {
                    const int m = m0 + wm * 64 + i * 16 + (lane >> 4) * 4 + r;
                    const int b = m >> 11, s = m & (SS - 1);
                    outh[(((size_t)(b * HH + h)) * SS + s) * DKV + d] =
                        __float2bfloat16(acc[i][j][r] + bvv);
                }
            }
        }
    } else {
        short* vT = (short*)outh;
        #pragma unroll
        for (int j = 0; j < 4; j++) {
            const int col = n0 + wn * 64 + j * 16 + lr;
            const float bvv = bias[col];
            const int h = col >> 6, d = col & 63;
            #pragma unroll
            for (int i = 0; i < 4; i++) {
                const int m = m0 + wm * 64 + i * 16 + (lane >> 4) * 4;
                const int b = m >> 11, s = m & (SS - 1);
                short4_t pk;
                #pragma unroll
                for (int r = 0; r < 4; r++) pk[r] = f2bf(acc[i][j][r] + bvv);
                *(short4_t*)(vT + ((size_t)(b * HH + h) * DKV + d) * SS + s) = pk;
            }
        }
    }
}

// ---------------------------------------------------------------------------
// Output GEMM: out[M,N] (fp32) = ctx[M,K](bf16) @ wo[K,N] + bo + residual
// ---------------------------------------------------------------------------
__global__ __launch_bounds__(256) void outproj_kernel(
    const __hip_bfloat16* __restrict__ Actx, const float* __restrict__ W,
    const float* __restrict__ bias, const float* __restrict__ resid,
    float* __restrict__ out)
{
    __shared__ __align__(16) short As[128][40];
    __shared__ __align__(16) short Bs[128][40];
    const int t = threadIdx.x;
    const int lane = t & 63;
    const int wave = t >> 6;
    const int wm = wave >> 1, wn = wave & 1;
    const int m0 = blockIdx.x * 128, n0 = blockIdx.y * 128;
    const int lr = lane & 15;
    const int kb = (lane >> 4) * 8;

    f32x4 acc[4][4] = {};

    for (int k0 = 0; k0 < DD; k0 += 32) {
        __syncthreads();
        {
            const int row = t >> 1, kk = (t & 1) * 16;
            const short8* src = (const short8*)((const short*)Actx + (size_t)(m0 + row) * DD + k0 + kk);
            *(short8*)&As[row][kk]     = src[0];
            *(short8*)&As[row][kk + 8] = src[1];
        }
        {
            const int kk = t >> 3, c0 = (t & 7) * 16;
            const float* src = W + (size_t)(k0 + kk) * DD + n0 + c0;
            #pragma unroll
            for (int i = 0; i < 16; i += 4) {
                float4 f = *(const float4*)(src + i);
                Bs[c0 + i + 0][kk] = f2bf(f.x);
                Bs[c0 + i + 1][kk] = f2bf(f.y);
                Bs[c0 + i + 2][kk] = f2bf(f.z);
                Bs[c0 + i + 3][kk] = f2bf(f.w);
            }
        }
        __syncthreads();
        short8 af[4], bfr[4];
        #pragma unroll
        for (int i = 0; i < 4; i++) af[i]  = *(const short8*)&As[wm * 64 + i * 16 + lr][kb];
        #pragma unroll
        for (int j = 0; j < 4; j++) bfr[j] = *(const short8*)&Bs[wn * 64 + j * 16 + lr][kb];
        #pragma unroll
        for (int i = 0; i < 4; i++)
            #pragma unroll
            for (int j = 0; j < 4; j++)
                acc[i][j] = MFMA16(af[i], bfr[j], acc[i][j]);
    }

    #pragma unroll
    for (int j = 0; j < 4; j++) {
        const int col = n0 + wn * 64 + j * 16 + lr;
        const float bvv = bias[col];
        #pragma unroll
        for (int i = 0; i < 4; i++) {
            #pragma unroll
            for (int r = 0; r < 4; r++) {
                const int m = m0 + wm * 64 + i * 16 + (lane >> 4) * 4 + r;
                out[(size_t)m * DD + col] = acc[i][j][r] + bvv + resid[(size_t)m * DD + col];
            }
        }
    }
}

// ---------------------------------------------------------------------------
// Attention v4: 8 waves / 512 threads per block, 128 q-rows per block.
// Pass 1 reads the raw int32 mask (coalesced), ballot-packs to bits (for
// pass 2), computes row sums. Pass 2 recomputes scores, writes attn fp32
// + context. K and V^T staged in LDS (coalesced); Q frags in registers.
// ---------------------------------------------------------------------------
__global__ __launch_bounds__(512) void attn_kernel(
    const __hip_bfloat16* __restrict__ qh, const __hip_bfloat16* __restrict__ kh,
    const __hip_bfloat16* __restrict__ vT, const int* __restrict__ mask,
    unsigned long long* __restrict__ bits,
    float* __restrict__ attn, __hip_bfloat16* __restrict__ ctx)
{
    __shared__ __align__(16) short Ks[64][72];
    __shared__ __align__(16) short VsT[64][72];   // VsT[d][k]
    __shared__ __align__(16) short Ps[8][16][72]; // per-wave P tile
    const int t = threadIdx.x, lane = t & 63, w = t >> 6;

    // XCD grouping: 512 blocks, 8 XCDs -> XCD x gets logical [64x,64x+64) = 4 heads
    const int logical = (blockIdx.x & 7) * 64 + (blockIdx.x >> 3);
    const int qt = logical & 15;
    const int bh = logical >> 4;
    const int h = bh & (HH - 1);
    const int b = bh >> 4;
    const int q0w = qt * 128 + w * 16;            // this wave's 16 q-rows
    const size_t headbase = (size_t)bh * SS * DKV;
    const int lr = lane & 15;
    const int kb = (lane >> 4) * 8;
    const int Q4 = lane >> 4;
    const int rbase = Q4 * 4;

    const short* kbase = (const short*)kh + headbase;
    const short* vbase = (const short*)vT + (size_t)bh * DKV * SS;
    const int* mbase = mask + ((size_t)b * SS + q0w) * SS;
    unsigned long long* bitrow = bits + ((size_t)b * SS + q0w) * (SS / 64);

    // Q fragments (resident; one-time scattered load, negligible)
    const short* qrp = (const short*)qh + headbase + (size_t)(q0w + lr) * DKV;
    const short8 aq0 = *(const short8*)(qrp + kb);
    const short8 aq1 = *(const short8*)(qrp + 32 + kb);

    float lsum[4] = {0.f, 0.f, 0.f, 0.f};

    // ---------------- pass 1: mask pack + row sums ----------------
    for (int kt = 0; kt < 32; ++kt) {
        const int k0 = kt * 64;
        __syncthreads();
        {
            const int row = t >> 3, c = (t & 7) * 8;
            *(short8*)&Ks[row][c] = *(const short8*)(kbase + (size_t)(k0 + row) * DKV + c);
        }
        __syncthreads();
        f32x4 sc[4];
        #pragma unroll
        for (int fc = 0; fc < 4; ++fc) {
            short8 bk0 = *(const short8*)&Ks[fc * 16 + lr][kb];
            short8 bk1 = *(const short8*)&Ks[fc * 16 + lr][32 + kb];
            f32x4 s = {0.f, 0.f, 0.f, 0.f};
            s = MFMA16(aq0, bk0, s);
            s = MFMA16(aq1, bk1, s);
            sc[fc] = s;
        }
        // read raw mask (64B coalesced per quarter-wave) + ballot-pack
        unsigned long long mw[4] = {0ull, 0ull, 0ull, 0ull};
        #pragma unroll
        for (int fc = 0; fc < 4; ++fc) {
            #pragma unroll
            for (int r = 0; r < 4; ++r) {
                const int mv = mbase[(size_t)(rbase + r) * SS + k0 + fc * 16 + lr];
                const unsigned long long bal = __ballot(mv != 0);
                mw[r] |= ((bal >> (16 * Q4)) & 0xFFFFull) << (16 * fc);
            }
        }
        if (lr == 0) {
            #pragma unroll
            for (int r = 0; r < 4; ++r)
                bitrow[(size_t)(rbase + r) * (SS / 64) + kt] = mw[r];
        }
        #pragma unroll
        for (int fc = 0; fc < 4; ++fc)
            #pragma unroll
            for (int r = 0; r < 4; ++r) {
                const bool masked = (mw[r] >> (fc * 16 + lr)) & 1ull;
                lsum[r] += masked ? 0.f : __expf(sc[fc][r] * 0.125f);
            }
    }
    #pragma unroll
    for (int r = 0; r < 4; r++) {
        float s = lsum[r];
        s += __shfl_xor(s, 1);
        s += __shfl_xor(s, 2);
        s += __shfl_xor(s, 4);
        s += __shfl_xor(s, 8);
        lsum[r] = s;
    }
    float linv[4];
    #pragma unroll
    for (int r = 0; r < 4; r++) linv[r] = 1.f / lsum[r];

    f32x4 cacc[4] = {};
    float* arow = attn + ((size_t)bh * SS + q0w) * SS;

    // ---------------- pass 2: attn write + context ----------------
    for (int kt = 0; kt < 32; ++kt) {
        const int k0 = kt * 64;
        __syncthreads();
        {
            const int row = t >> 3, c = (t & 7) * 8;
            *(short8*)&Ks[row][c]  = *(const short8*)(kbase + (size_t)(k0 + row) * DKV + c);
            *(short8*)&VsT[row][c] = *(const short8*)(vbase + (size_t)row * SS + k0 + c);
        }
        __syncthreads();
        f32x4 sc[4];
        #pragma unroll
        for (int fc = 0; fc < 4; ++fc) {
            short8 bk0 = *(const short8*)&Ks[fc * 16 + lr][kb];
            short8 bk1 = *(const short8*)&Ks[fc * 16 + lr][32 + kb];
            f32x4 s = {0.f, 0.f, 0.f, 0.f};
            s = MFMA16(aq0, bk0, s);
            s = MFMA16(aq1, bk1, s);
            sc[fc] = s;
        }
        unsigned long long mw[4];
        #pragma unroll
        for (int r = 0; r < 4; ++r)
            mw[r] = bitrow[(size_t)(rbase + r) * (SS / 64) + kt];
        #pragma unroll
        for (int fc = 0; fc < 4; ++fc)
            #pragma unroll
            for (int r = 0; r < 4; ++r) {
                const bool masked = (mw[r] >> (fc * 16 + lr)) & 1ull;
                const float p = masked ? 0.f : __expf(sc[fc][r] * 0.125f) * linv[r];
                arow[(size_t)(rbase + r) * SS + k0 + fc * 16 + lr] = p;
                Ps[w][rbase + r][fc * 16 + lr] = f2bf(p);
            }
        // wave-internal LDS dependency (lgkmcnt handled by compiler)
        short8 ap0 = *(const short8*)&Ps[w][lr][kb];
        short8 ap1 = *(const short8*)&Ps[w][lr][32 + kb];
        #pragma unroll
        for (int fd = 0; fd < 4; ++fd) {
            short8 bv0 = *(const short8*)&VsT[fd * 16 + lr][kb];
            short8 bv1 = *(const short8*)&VsT[fd * 16 + lr][32 + kb];
            cacc[fd] = MFMA16(ap0, bv0, cacc[fd]);
            cacc[fd] = MFMA16(ap1, bv1, cacc[fd]);
        }
    }

    #pragma unroll
    for (int fd = 0; fd < 4; ++fd)
        #pragma unroll
        for (int r = 0; r < 4; r++) {
            const int qrow = q0w + rbase + r;
            ctx[((size_t)b * SS + qrow) * DD + h * DKV + fd * 16 + lr] =
                __float2bfloat16(cacc[fd][r]);
        }
}

// ---------------------------------------------------------------------------
// LayerNorm in place on out[4096][1024], biased var, eps=1e-5
// ---------------------------------------------------------------------------
__global__ __launch_bounds__(256) void ln_kernel(
    float* __restrict__ io, const float* __restrict__ g, const float* __restrict__ bta)
{
    const int row = blockIdx.x;
    const int t = threadIdx.x;
    float* p = io + (size_t)row * DD;
    float4 x = *(float4*)(p + t * 4);
    float s  = x.x + x.y + x.z + x.w;
    float s2 = x.x * x.x + x.y * x.y + x.z * x.z + x.w * x.w;
    #pragma unroll
    for (int off = 32; off; off >>= 1) {
        s  += __shfl_xor(s, off);
        s2 += __shfl_xor(s2, off);
    }
    __shared__ float as_[4], bs_[4];
    const int w = t >> 6, l = t & 63;
    if (!l) { as_[w] = s; bs_[w] = s2; }
    __syncthreads();
    s  = as_[0] + as_[1] + as_[2] + as_[3];
    s2 = bs_[0] + bs_[1] + bs_[2] + bs_[3];
    const float mu  = s * (1.f / DD);
    const float var = s2 * (1.f / DD) - mu * mu;
    const float rs  = rsqrtf(var + 1e-5f);
    float4 gv = *(const float4*)(g + t * 4);
    float4 bv = *(const float4*)(bta + t * 4);
    float4 o;
    o.x = (x.x - mu) * rs * gv.x + bv.x;
    o.y = (x.y - mu) * rs * gv.y + bv.y;
    o.z = (x.z - mu) * rs * gv.z + bv.z;
    o.w = (x.w - mu) * rs * gv.w + bv.w;
    *(float4*)(p + t * 4) = o;
}

// ---------------------------------------------------------------------------
extern "C" void kernel_launch(void* const* d_in, const int* in_sizes, int n_in,
                              void* d_out, int out_size, void* d_ws, size_t ws_size,
                              hipStream_t stream)
{
    (void)in_sizes; (void)n_in; (void)out_size; (void)ws_size;
    const float* q     = (const float*)d_in[0];
    const float* k     = (const float*)d_in[1];
    const float* v     = (const float*)d_in[2];
    const int*   mask  = (const int*)d_in[3];
    const float* wq    = (const float*)d_in[4];
    const float* bq    = (const float*)d_in[5];
    const float* wk    = (const float*)d_in[6];
    const float* bk    = (const float*)d_in[7];
    const float* wv    = (const float*)d_in[8];
    const float* bv    = (const float*)d_in[9];
    const float* wo    = (const float*)d_in[10];
    const float* bo    = (const float*)d_in[11];
    const float* gamma = (const float*)d_in[12];
    const float* beta  = (const float*)d_in[13];

    float* out  = (float*)d_out;                    // [B,S,D]
    float* attn = out + (size_t)BB * SS * DD;       // [B,H,S,S]

    const size_t hsz = (size_t)BB * HH * SS * DKV;  // 4,194,304
    __hip_bfloat16* qhp = (__hip_bfloat16*)d_ws;
    __hip_bfloat16* khp = qhp + hsz;
    __hip_bfloat16* vTp = khp + hsz;                // vT[b][h][d][s]
    __hip_bfloat16* ctx = vTp + hsz;
    unsigned long long* bits = (unsigned long long*)(ctx + hsz);  // 1 MB

    dim3 gg(32, 8, 3);
    proj3_kernel<<<gg, 256, 0, stream>>>(q, k, v, wq, wk, wv, bq, bk, bv, qhp, khp, vTp);
    attn_kernel<<<BB * HH * 16, 512, 0, stream>>>(qhp, khp, vTp, mask, bits, attn, ctx);
    dim3 go(32, 8);
    outproj_kernel<<<go, 256, 0, stream>>>(ctx, wo, bo, q, out);
    ln_kernel<<<BB * SS, 256, 0, stream>>>(out, gamma, beta);
}

// Round 5
// 406.521 us; speedup vs baseline: 1.5631x; 1.0353x over previous
//
#include <hip/hip_runtime.h>
#include <hip/hip_bf16.h>

#define BB 2
#define SS 2048
#define DD 1024
#define HH 16
#define DKV 64

typedef __attribute__((ext_vector_type(8))) short short8;
typedef __attribute__((ext_vector_type(4))) short short4_t;
typedef __attribute__((ext_vector_type(4))) float f32x4;

#define MFMA16(a, b, c) __builtin_amdgcn_mfma_f32_16x16x32_bf16(a, b, c, 0, 0, 0)

__device__ __forceinline__ short f2bf(float f) {
    __hip_bfloat16 h = __float2bfloat16(f);
    union { __hip_bfloat16 h; short s; } u;
    u.h = h;
    return u.s;
}

// ---------------------------------------------------------------------------
// Fused projection GEMMs (q/k/v). z=0,1 -> head-row-major [b][h][s][64];
// z=2 (V) -> transposed per head: vT[b][h][d][s].
// ---------------------------------------------------------------------------
__global__ __launch_bounds__(256) void proj3_kernel(
    const float* __restrict__ A0, const float* __restrict__ A1, const float* __restrict__ A2,
    const float* __restrict__ W0, const float* __restrict__ W1, const float* __restrict__ W2,
    const float* __restrict__ bq, const float* __restrict__ bk, const float* __restrict__ bv,
    __hip_bfloat16* __restrict__ o0, __hip_bfloat16* __restrict__ o1, __hip_bfloat16* __restrict__ o2)
{
    const int z = blockIdx.z;
    const float* A = (z == 0) ? A0 : (z == 1) ? A1 : A2;
    const float* W = (z == 0) ? W0 : (z == 1) ? W1 : W2;
    const float* bias = (z == 0) ? bq : (z == 1) ? bk : bv;
    __hip_bfloat16* outh = (z == 0) ? o0 : (z == 1) ? o1 : o2;

    __shared__ __align__(16) short As[128][40];
    __shared__ __align__(16) short Bs[128][40];  // transposed: Bs[col][k]
    const int t = threadIdx.x;
    const int lane = t & 63;
    const int wave = t >> 6;
    const int wm = wave >> 1, wn = wave & 1;
    const int m0 = blockIdx.x * 128, n0 = blockIdx.y * 128;
    const int lr = lane & 15;
    const int kb = (lane >> 4) * 8;

    f32x4 acc[4][4] = {};

    for (int k0 = 0; k0 < DD; k0 += 32) {
        __syncthreads();
        {
            const int row = t >> 1, kk = (t & 1) * 16;
            const float* src = A + (size_t)(m0 + row) * DD + k0 + kk;
            float4 fa = *(const float4*)(src);
            float4 fb = *(const float4*)(src + 4);
            float4 fc = *(const float4*)(src + 8);
            float4 fd = *(const float4*)(src + 12);
            short8 v0 = { f2bf(fa.x), f2bf(fa.y), f2bf(fa.z), f2bf(fa.w),
                          f2bf(fb.x), f2bf(fb.y), f2bf(fb.z), f2bf(fb.w) };
            short8 v1 = { f2bf(fc.x), f2bf(fc.y), f2bf(fc.z), f2bf(fc.w),
                          f2bf(fd.x), f2bf(fd.y), f2bf(fd.z), f2bf(fd.w) };
            *(short8*)&As[row][kk]     = v0;
            *(short8*)&As[row][kk + 8] = v1;
        }
        {
            const int kk = t >> 3, c0 = (t & 7) * 16;
            const float* src = W + (size_t)(k0 + kk) * DD + n0 + c0;
            #pragma unroll
            for (int i = 0; i < 16; i += 4) {
                float4 f = *(const float4*)(src + i);
                Bs[c0 + i + 0][kk] = f2bf(f.x);
                Bs[c0 + i + 1][kk] = f2bf(f.y);
                Bs[c0 + i + 2][kk] = f2bf(f.z);
                Bs[c0 + i + 3][kk] = f2bf(f.w);
            }
        }
        __syncthreads();
        short8 af[4], bfr[4];
        #pragma unroll
        for (int i = 0; i < 4; i++) af[i]  = *(const short8*)&As[wm * 64 + i * 16 + lr][kb];
        #pragma unroll
        for (int j = 0; j < 4; j++) bfr[j] = *(const short8*)&Bs[wn * 64 + j * 16 + lr][kb];
        #pragma unroll
        for (int i = 0; i < 4; i++)
            #pragma unroll
            for (int j = 0; j < 4; j++)
                acc[i][j] = MFMA16(af[i], bfr[j], acc[i][j]);
    }

    if (z != 2) {
        #pragma unroll
        for (int j = 0; j < 4; j++) {
            const int col = n0 + wn * 64 + j * 16 + lr;
            const float bvv = bias[col];
            const int h = col >> 6, d = col & 63;
            #pragma unroll
            for (int i = 0; i < 4; i++) {
                #pragma unroll
                for (int r = 0; r < 4; r++) {
                    const int m = m0 + wm * 64 + i * 16 + (lane >> 4) * 4 + r;
                    const int b = m >> 11, s = m & (SS - 1);
                    outh[(((size_t)(b * HH + h)) * SS + s) * DKV + d] =
                        __float2bfloat16(acc[i][j][r] + bvv);
                }
            }
        }
    } else {
        short* vT = (short*)outh;
        #pragma unroll
        for (int j = 0; j < 4; j++) {
            const int col = n0 + wn * 64 + j * 16 + lr;
            const float bvv = bias[col];
            const int h = col >> 6, d = col & 63;
            #pragma unroll
            for (int i = 0; i < 4; i++) {
                const int m = m0 + wm * 64 + i * 16 + (lane >> 4) * 4;
                const int b = m >> 11, s = m & (SS - 1);
                short4_t pk;
                #pragma unroll
                for (int r = 0; r < 4; r++) pk[r] = f2bf(acc[i][j][r] + bvv);
                *(short4_t*)(vT + ((size_t)(b * HH + h) * DKV + d) * SS + s) = pk;
            }
        }
    }
}

// ---------------------------------------------------------------------------
// Output GEMM: out[M,N] (fp32) = ctx[M,K](bf16) @ wo[K,N] + bo + residual
// ---------------------------------------------------------------------------
__global__ __launch_bounds__(256) void outproj_kernel(
    const __hip_bfloat16* __restrict__ Actx, const float* __restrict__ W,
    const float* __restrict__ bias, const float* __restrict__ resid,
    float* __restrict__ out)
{
    __shared__ __align__(16) short As[128][40];
    __shared__ __align__(16) short Bs[128][40];
    const int t = threadIdx.x;
    const int lane = t & 63;
    const int wave = t >> 6;
    const int wm = wave >> 1, wn = wave & 1;
    const int m0 = blockIdx.x * 128, n0 = blockIdx.y * 128;
    const int lr = lane & 15;
    const int kb = (lane >> 4) * 8;

    f32x4 acc[4][4] = {};

    for (int k0 = 0; k0 < DD; k0 += 32) {
        __syncthreads();
        {
            const int row = t >> 1, kk = (t & 1) * 16;
            const short8* src = (const short8*)((const short*)Actx + (size_t)(m0 + row) * DD + k0 + kk);
            *(short8*)&As[row][kk]     = src[0];
            *(short8*)&As[row][kk + 8] = src[1];
        }
        {
            const int kk = t >> 3, c0 = (t & 7) * 16;
            const float* src = W + (size_t)(k0 + kk) * DD + n0 + c0;
            #pragma unroll
            for (int i = 0; i < 16; i += 4) {
                float4 f = *(const float4*)(src + i);
                Bs[c0 + i + 0][kk] = f2bf(f.x);
                Bs[c0 + i + 1][kk] = f2bf(f.y);
                Bs[c0 + i + 2][kk] = f2bf(f.z);
                Bs[c0 + i + 3][kk] = f2bf(f.w);
            }
        }
        __syncthreads();
        short8 af[4], bfr[4];
        #pragma unroll
        for (int i = 0; i < 4; i++) af[i]  = *(const short8*)&As[wm * 64 + i * 16 + lr][kb];
        #pragma unroll
        for (int j = 0; j < 4; j++) bfr[j] = *(const short8*)&Bs[wn * 64 + j * 16 + lr][kb];
        #pragma unroll
        for (int i = 0; i < 4; i++)
            #pragma unroll
            for (int j = 0; j < 4; j++)
                acc[i][j] = MFMA16(af[i], bfr[j], acc[i][j]);
    }

    #pragma unroll
    for (int j = 0; j < 4; j++) {
        const int col = n0 + wn * 64 + j * 16 + lr;
        const float bvv = bias[col];
        #pragma unroll
        for (int i = 0; i < 4; i++) {
            #pragma unroll
            for (int r = 0; r < 4; r++) {
                const int m = m0 + wm * 64 + i * 16 + (lane >> 4) * 4 + r;
                out[(size_t)m * DD + col] = acc[i][j][r] + bvv + resid[(size_t)m * DD + col];
            }
        }
    }
}

// ---------------------------------------------------------------------------
// Attention v5: 8 waves / 512 threads, 128 q-rows per block.
// Double-buffered LDS staging with async prefetch: each iter issues next
// tile's global loads FIRST, computes from current buffer, ds_writes the
// prefetched regs to the other buffer, then ONE barrier. Latency hides
// under compute (T14); barrier count halved vs v4.
// ---------------------------------------------------------------------------
__global__ __launch_bounds__(512) void attn_kernel(
    const __hip_bfloat16* __restrict__ qh, const __hip_bfloat16* __restrict__ kh,
    const __hip_bfloat16* __restrict__ vT, const int* __restrict__ mask,
    unsigned long long* __restrict__ bits,
    float* __restrict__ attn, __hip_bfloat16* __restrict__ ctx)
{
    __shared__ __align__(16) short Ks[2][64][72];
    __shared__ __align__(16) short Vs[2][64][72];   // Vs[d][k]
    __shared__ __align__(16) short Ps[8][16][72];   // per-wave P tile
    const int t = threadIdx.x, lane = t & 63, w = t >> 6;

    // XCD grouping: 512 blocks, 8 XCDs -> XCD x gets 4 contiguous heads
    const int logical = (blockIdx.x & 7) * 64 + (blockIdx.x >> 3);
    const int qt = logical & 15;
    const int bh = logical >> 4;
    const int h = bh & (HH - 1);
    const int b = bh >> 4;
    const int q0w = qt * 128 + w * 16;            // this wave's 16 q-rows
    const size_t headbase = (size_t)bh * SS * DKV;
    const int lr = lane & 15;
    const int kb = (lane >> 4) * 8;
    const int Q4 = lane >> 4;
    const int rbase = Q4 * 4;

    const short* kbase = (const short*)kh + headbase;
    const short* vbase = (const short*)vT + (size_t)bh * DKV * SS;
    const int* mbase = mask + ((size_t)b * SS + q0w) * SS;
    unsigned long long* bitrow = bits + ((size_t)b * SS + q0w) * (SS / 64);

    // staging coords: each thread one short8 per tile per matrix
    const int srow = t >> 3, sc8 = (t & 7) * 8;
    const short* kstg = kbase + (size_t)srow * DKV + sc8;   // + kt*64*DKV
    const short* vstg = vbase + (size_t)srow * SS + sc8;    // + kt*64

    // Q fragments (resident)
    const short* qrp = (const short*)qh + headbase + (size_t)(q0w + lr) * DKV;
    const short8 aq0 = *(const short8*)(qrp + kb);
    const short8 aq1 = *(const short8*)(qrp + 32 + kb);

    float lsum[4] = {0.f, 0.f, 0.f, 0.f};

    // ---------------- pass 1: mask pack + row sums ----------------
    {
        short8 kreg = *(const short8*)(kstg);
        *(short8*)&Ks[0][srow][sc8] = kreg;
        __syncthreads();
        for (int kt = 0; kt < 32; ++kt) {
            const int cur = kt & 1;
            const int k0 = kt * 64;
            if (kt + 1 < 32)
                kreg = *(const short8*)(kstg + (size_t)(kt + 1) * 64 * DKV);
            f32x4 sc[4];
            #pragma unroll
            for (int fc = 0; fc < 4; ++fc) {
                short8 bk0 = *(const short8*)&Ks[cur][fc * 16 + lr][kb];
                short8 bk1 = *(const short8*)&Ks[cur][fc * 16 + lr][32 + kb];
                f32x4 s = {0.f, 0.f, 0.f, 0.f};
                s = MFMA16(aq0, bk0, s);
                s = MFMA16(aq1, bk1, s);
                sc[fc] = s;
            }
            // read raw mask (coalesced per quarter-wave) + ballot-pack
            unsigned long long mw[4] = {0ull, 0ull, 0ull, 0ull};
            #pragma unroll
            for (int fc = 0; fc < 4; ++fc) {
                #pragma unroll
                for (int r = 0; r < 4; ++r) {
                    const int mv = mbase[(size_t)(rbase + r) * SS + k0 + fc * 16 + lr];
                    const unsigned long long bal = __ballot(mv != 0);
                    mw[r] |= ((bal >> (16 * Q4)) & 0xFFFFull) << (16 * fc);
                }
            }
            if (lr == 0) {
                #pragma unroll
                for (int r = 0; r < 4; ++r)
                    bitrow[(size_t)(rbase + r) * (SS / 64) + kt] = mw[r];
            }
            #pragma unroll
            for (int fc = 0; fc < 4; ++fc)
                #pragma unroll
                for (int r = 0; r < 4; ++r) {
                    const bool masked = (mw[r] >> (fc * 16 + lr)) & 1ull;
                    lsum[r] += masked ? 0.f : __expf(sc[fc][r] * 0.125f);
                }
            if (kt + 1 < 32)
                *(short8*)&Ks[cur ^ 1][srow][sc8] = kreg;
            __syncthreads();
        }
    }
    #pragma unroll
    for (int r = 0; r < 4; r++) {
        float s = lsum[r];
        s += __shfl_xor(s, 1);
        s += __shfl_xor(s, 2);
        s += __shfl_xor(s, 4);
        s += __shfl_xor(s, 8);
        lsum[r] = s;
    }
    float linv[4];
    #pragma unroll
    for (int r = 0; r < 4; r++) linv[r] = 1.f / lsum[r];

    f32x4 cacc[4] = {};
    float* arow = attn + ((size_t)bh * SS + q0w) * SS;

    // ---------------- pass 2: attn write + context ----------------
    {
        short8 kreg = *(const short8*)(kstg);
        short8 vreg = *(const short8*)(vstg);
        *(short8*)&Ks[0][srow][sc8] = kreg;
        *(short8*)&Vs[0][srow][sc8] = vreg;
        __syncthreads();
        for (int kt = 0; kt < 32; ++kt) {
            const int cur = kt & 1;
            const int k0 = kt * 64;
            if (kt + 1 < 32) {
                kreg = *(const short8*)(kstg + (size_t)(kt + 1) * 64 * DKV);
                vreg = *(const short8*)(vstg + (size_t)(kt + 1) * 64);
            }
            f32x4 sc[4];
            #pragma unroll
            for (int fc = 0; fc < 4; ++fc) {
                short8 bk0 = *(const short8*)&Ks[cur][fc * 16 + lr][kb];
                short8 bk1 = *(const short8*)&Ks[cur][fc * 16 + lr][32 + kb];
                f32x4 s = {0.f, 0.f, 0.f, 0.f};
                s = MFMA16(aq0, bk0, s);
                s = MFMA16(aq1, bk1, s);
                sc[fc] = s;
            }
            unsigned long long mw[4];
            #pragma unroll
            for (int r = 0; r < 4; ++r)
                mw[r] = bitrow[(size_t)(rbase + r) * (SS / 64) + kt];
            #pragma unroll
            for (int fc = 0; fc < 4; ++fc)
                #pragma unroll
                for (int r = 0; r < 4; ++r) {
                    const bool masked = (mw[r] >> (fc * 16 + lr)) & 1ull;
                    const float p = masked ? 0.f : __expf(sc[fc][r] * 0.125f) * linv[r];
                    arow[(size_t)(rbase + r) * SS + k0 + fc * 16 + lr] = p;
                    Ps[w][rbase + r][fc * 16 + lr] = f2bf(p);
                }
            // wave-internal LDS dependency (lgkmcnt handled by compiler)
            short8 ap0 = *(const short8*)&Ps[w][lr][kb];
            short8 ap1 = *(const short8*)&Ps[w][lr][32 + kb];
            #pragma unroll
            for (int fd = 0; fd < 4; ++fd) {
                short8 bv0 = *(const short8*)&Vs[cur][fd * 16 + lr][kb];
                short8 bv1 = *(const short8*)&Vs[cur][fd * 16 + lr][32 + kb];
                cacc[fd] = MFMA16(ap0, bv0, cacc[fd]);
                cacc[fd] = MFMA16(ap1, bv1, cacc[fd]);
            }
            if (kt + 1 < 32) {
                *(short8*)&Ks[cur ^ 1][srow][sc8] = kreg;
                *(short8*)&Vs[cur ^ 1][srow][sc8] = vreg;
            }
            __syncthreads();
        }
    }

    #pragma unroll
    for (int fd = 0; fd < 4; ++fd)
        #pragma unroll
        for (int r = 0; r < 4; r++) {
            const int qrow = q0w + rbase + r;
            ctx[((size_t)b * SS + qrow) * DD + h * DKV + fd * 16 + lr] =
                __float2bfloat16(cacc[fd][r]);
        }
}

// ---------------------------------------------------------------------------
// LayerNorm in place on out[4096][1024], biased var, eps=1e-5
// ---------------------------------------------------------------------------
__global__ __launch_bounds__(256) void ln_kernel(
    float* __restrict__ io, const float* __restrict__ g, const float* __restrict__ bta)
{
    const int row = blockIdx.x;
    const int t = threadIdx.x;
    float* p = io + (size_t)row * DD;
    float4 x = *(float4*)(p + t * 4);
    float s  = x.x + x.y + x.z + x.w;
    float s2 = x.x * x.x + x.y * x.y + x.z * x.z + x.w * x.w;
    #pragma unroll
    for (int off = 32; off; off >>= 1) {
        s  += __shfl_xor(s, off);
        s2 += __shfl_xor(s2, off);
    }
    __shared__ float as_[4], bs_[4];
    const int w = t >> 6, l = t & 63;
    if (!l) { as_[w] = s; bs_[w] = s2; }
    __syncthreads();
    s  = as_[0] + as_[1] + as_[2] + as_[3];
    s2 = bs_[0] + bs_[1] + bs_[2] + bs_[3];
    const float mu  = s * (1.f / DD);
    const float var = s2 * (1.f / DD) - mu * mu;
    const float rs  = rsqrtf(var + 1e-5f);
    float4 gv = *(const float4*)(g + t * 4);
    float4 bv = *(const float4*)(bta + t * 4);
    float4 o;
    o.x = (x.x - mu) * rs * gv.x + bv.x;
    o.y = (x.y - mu) * rs * gv.y + bv.y;
    o.z = (x.z - mu) * rs * gv.z + bv.z;
    o.w = (x.w - mu) * rs * gv.w + bv.w;
    *(float4*)(p + t * 4) = o;
}

// ---------------------------------------------------------------------------
extern "C" void kernel_launch(void* const* d_in, const int* in_sizes, int n_in,
                              void* d_out, int out_size, void* d_ws, size_t ws_size,
                              hipStream_t stream)
{
    (void)in_sizes; (void)n_in; (void)out_size; (void)ws_size;
    const float* q     = (const float*)d_in[0];
    const float* k     = (const float*)d_in[1];
    const float* v     = (const float*)d_in[2];
    const int*   mask  = (const int*)d_in[3];
    const float* wq    = (const float*)d_in[4];
    const float* bq    = (const float*)d_in[5];
    const float* wk    = (const float*)d_in[6];
    const float* bk    = (const float*)d_in[7];
    const float* wv    = (const float*)d_in[8];
    const float* bv    = (const float*)d_in[9];
    const float* wo    = (const float*)d_in[10];
    const float* bo    = (const float*)d_in[11];
    const float* gamma = (const float*)d_in[12];
    const float* beta  = (const float*)d_in[13];

    float* out  = (float*)d_out;                    // [B,S,D]
    float* attn = out + (size_t)BB * SS * DD;       // [B,H,S,S]

    const size_t hsz = (size_t)BB * HH * SS * DKV;  // 4,194,304
    __hip_bfloat16* qhp = (__hip_bfloat16*)d_ws;
    __hip_bfloat16* khp = qhp + hsz;
    __hip_bfloat16* vTp = khp + hsz;                // vT[b][h][d][s]
    __hip_bfloat16* ctx = vTp + hsz;
    unsigned long long* bits = (unsigned long long*)(ctx + hsz);  // 1 MB

    dim3 gg(32, 8, 3);
    proj3_kernel<<<gg, 256, 0, stream>>>(q, k, v, wq, wk, wv, bq, bk, bv, qhp, khp, vTp);
    attn_kernel<<<BB * HH * 16, 512, 0, stream>>>(qhp, khp, vTp, mask, bits, attn, ctx);
    dim3 go(32, 8);
    outproj_kernel<<<go, 256, 0, stream>>>(ctx, wo, bo, q, out);
    ln_kernel<<<BB * SS, 256, 0, stream>>>(out, gamma, beta);
}

// Round 6
// 404.667 us; speedup vs baseline: 1.5703x; 1.0046x over previous
//
#include <hip/hip_runtime.h>
#include <hip/hip_bf16.h>

#define BB 2
#define SS 2048
#define DD 1024
#define HH 16
#define DKV 64

typedef __attribute__((ext_vector_type(8))) short short8;
typedef __attribute__((ext_vector_type(4))) short short4_t;
typedef __attribute__((ext_vector_type(4))) float f32x4;

#define MFMA16(a, b, c) __builtin_amdgcn_mfma_f32_16x16x32_bf16(a, b, c, 0, 0, 0)

__device__ __forceinline__ short f2bf(float f) {
    __hip_bfloat16 h = __float2bfloat16(f);
    union { __hip_bfloat16 h; short s; } u;
    u.h = h;
    return u.s;
}

// ---------------------------------------------------------------------------
// Fused projection GEMMs + mask pack.
// z=0: mask bit-pack (256 blocks stream the 537MB mask -> 1MB bits),
//      dispatched FIRST so its BW demand overlaps proj compute.
// z=1,2 -> q,k head-row-major [b][h][s][64]; z=3 -> V transposed vT[b][h][d][s].
// ---------------------------------------------------------------------------
__global__ __launch_bounds__(256) void proj3_kernel(
    const float* __restrict__ A0, const float* __restrict__ A1, const float* __restrict__ A2,
    const float* __restrict__ W0, const float* __restrict__ W1, const float* __restrict__ W2,
    const float* __restrict__ bq, const float* __restrict__ bk, const float* __restrict__ bv,
    __hip_bfloat16* __restrict__ o0, __hip_bfloat16* __restrict__ o1, __hip_bfloat16* __restrict__ o2,
    const int* __restrict__ mask, unsigned long long* __restrict__ bits)
{
    const int t = threadIdx.x;
    const int lane = t & 63;
    const int wave = t >> 6;

    if (blockIdx.z == 0) {
        // ---- mask pack: 256 blocks x 4 waves; each wave 128 words ----
        const int bid = blockIdx.y * 32 + blockIdx.x;       // 0..255
        const int base = bid * 512 + wave * 128;
        #pragma unroll 4
        for (int wi = base; wi < base + 128; ++wi) {
            const int mv = mask[(size_t)wi * 64 + lane];
            const unsigned long long bal = __ballot(mv != 0);
            if (lane == 0) bits[wi] = bal;
        }
        return;
    }

    const int z = blockIdx.z - 1;
    const float* A = (z == 0) ? A0 : (z == 1) ? A1 : A2;
    const float* W = (z == 0) ? W0 : (z == 1) ? W1 : W2;
    const float* bias = (z == 0) ? bq : (z == 1) ? bk : bv;
    __hip_bfloat16* outh = (z == 0) ? o0 : (z == 1) ? o1 : o2;

    __shared__ __align__(16) short As[128][40];
    __shared__ __align__(16) short Bs[128][40];  // transposed: Bs[col][k]
    const int wm = wave >> 1, wn = wave & 1;
    const int m0 = blockIdx.x * 128, n0 = blockIdx.y * 128;
    const int lr = lane & 15;
    const int kb = (lane >> 4) * 8;

    f32x4 acc[4][4] = {};

    for (int k0 = 0; k0 < DD; k0 += 32) {
        __syncthreads();
        {
            const int row = t >> 1, kk = (t & 1) * 16;
            const float* src = A + (size_t)(m0 + row) * DD + k0 + kk;
            float4 fa = *(const float4*)(src);
            float4 fb = *(const float4*)(src + 4);
            float4 fc = *(const float4*)(src + 8);
            float4 fd = *(const float4*)(src + 12);
            short8 v0 = { f2bf(fa.x), f2bf(fa.y), f2bf(fa.z), f2bf(fa.w),
                          f2bf(fb.x), f2bf(fb.y), f2bf(fb.z), f2bf(fb.w) };
            short8 v1 = { f2bf(fc.x), f2bf(fc.y), f2bf(fc.z), f2bf(fc.w),
                          f2bf(fd.x), f2bf(fd.y), f2bf(fd.z), f2bf(fd.w) };
            *(short8*)&As[row][kk]     = v0;
            *(short8*)&As[row][kk + 8] = v1;
        }
        {
            const int kk = t >> 3, c0 = (t & 7) * 16;
            const float* src = W + (size_t)(k0 + kk) * DD + n0 + c0;
            #pragma unroll
            for (int i = 0; i < 16; i += 4) {
                float4 f = *(const float4*)(src + i);
                Bs[c0 + i + 0][kk] = f2bf(f.x);
                Bs[c0 + i + 1][kk] = f2bf(f.y);
                Bs[c0 + i + 2][kk] = f2bf(f.z);
                Bs[c0 + i + 3][kk] = f2bf(f.w);
            }
        }
        __syncthreads();
        short8 af[4], bfr[4];
        #pragma unroll
        for (int i = 0; i < 4; i++) af[i]  = *(const short8*)&As[wm * 64 + i * 16 + lr][kb];
        #pragma unroll
        for (int j = 0; j < 4; j++) bfr[j] = *(const short8*)&Bs[wn * 64 + j * 16 + lr][kb];
        #pragma unroll
        for (int i = 0; i < 4; i++)
            #pragma unroll
            for (int j = 0; j < 4; j++)
                acc[i][j] = MFMA16(af[i], bfr[j], acc[i][j]);
    }

    if (z != 2) {
        #pragma unroll
        for (int j = 0; j < 4; j++) {
            const int col = n0 + wn * 64 + j * 16 + lr;
            const float bvv = bias[col];
            const int h = col >> 6, d = col & 63;
            #pragma unroll
            for (int i = 0; i < 4; i++) {
                #pragma unroll
                for (int r = 0; r < 4; r++) {
                    const int m = m0 + wm * 64 + i * 16 + (lane >> 4) * 4 + r;
                    const int b = m >> 11, s = m & (SS - 1);
                    outh[(((size_t)(b * HH + h)) * SS + s) * DKV + d] =
                        __float2bfloat16(acc[i][j][r] + bvv);
                }
            }
        }
    } else {
        short* vT = (short*)outh;
        #pragma unroll
        for (int j = 0; j < 4; j++) {
            const int col = n0 + wn * 64 + j * 16 + lr;
            const float bvv = bias[col];
            const int h = col >> 6, d = col & 63;
            #pragma unroll
            for (int i = 0; i < 4; i++) {
                const int m = m0 + wm * 64 + i * 16 + (lane >> 4) * 4;
                const int b = m >> 11, s = m & (SS - 1);
                short4_t pk;
                #pragma unroll
                for (int r = 0; r < 4; r++) pk[r] = f2bf(acc[i][j][r] + bvv);
                *(short4_t*)(vT + ((size_t)(b * HH + h) * DKV + d) * SS + s) = pk;
            }
        }
    }
}

// ---------------------------------------------------------------------------
// Output GEMM: out[M,N] (fp32) = ctx[M,K](bf16) @ wo[K,N] + bo + residual
// ---------------------------------------------------------------------------
__global__ __launch_bounds__(256) void outproj_kernel(
    const __hip_bfloat16* __restrict__ Actx, const float* __restrict__ W,
    const float* __restrict__ bias, const float* __restrict__ resid,
    float* __restrict__ out)
{
    __shared__ __align__(16) short As[128][40];
    __shared__ __align__(16) short Bs[128][40];
    const int t = threadIdx.x;
    const int lane = t & 63;
    const int wave = t >> 6;
    const int wm = wave >> 1, wn = wave & 1;
    const int m0 = blockIdx.x * 128, n0 = blockIdx.y * 128;
    const int lr = lane & 15;
    const int kb = (lane >> 4) * 8;

    f32x4 acc[4][4] = {};

    for (int k0 = 0; k0 < DD; k0 += 32) {
        __syncthreads();
        {
            const int row = t >> 1, kk = (t & 1) * 16;
            const short8* src = (const short8*)((const short*)Actx + (size_t)(m0 + row) * DD + k0 + kk);
            *(short8*)&As[row][kk]     = src[0];
            *(short8*)&As[row][kk + 8] = src[1];
        }
        {
            const int kk = t >> 3, c0 = (t & 7) * 16;
            const float* src = W + (size_t)(k0 + kk) * DD + n0 + c0;
            #pragma unroll
            for (int i = 0; i < 16; i += 4) {
                float4 f = *(const float4*)(src + i);
                Bs[c0 + i + 0][kk] = f2bf(f.x);
                Bs[c0 + i + 1][kk] = f2bf(f.y);
                Bs[c0 + i + 2][kk] = f2bf(f.z);
                Bs[c0 + i + 3][kk] = f2bf(f.w);
            }
        }
        __syncthreads();
        short8 af[4], bfr[4];
        #pragma unroll
        for (int i = 0; i < 4; i++) af[i]  = *(const short8*)&As[wm * 64 + i * 16 + lr][kb];
        #pragma unroll
        for (int j = 0; j < 4; j++) bfr[j] = *(const short8*)&Bs[wn * 64 + j * 16 + lr][kb];
        #pragma unroll
        for (int i = 0; i < 4; i++)
            #pragma unroll
            for (int j = 0; j < 4; j++)
                acc[i][j] = MFMA16(af[i], bfr[j], acc[i][j]);
    }

    #pragma unroll
    for (int j = 0; j < 4; j++) {
        const int col = n0 + wn * 64 + j * 16 + lr;
        const float bvv = bias[col];
        #pragma unroll
        for (int i = 0; i < 4; i++) {
            #pragma unroll
            for (int r = 0; r < 4; r++) {
                const int m = m0 + wm * 64 + i * 16 + (lane >> 4) * 4 + r;
                out[(size_t)m * DD + col] = acc[i][j][r] + bvv + resid[(size_t)m * DD + col];
            }
        }
    }
}

// ---------------------------------------------------------------------------
// Attention v6: 8 waves / 512 threads, 128 q-rows per block.
// Mask arrives pre-packed in bits (1MB, produced by proj3 z=0, L2-resident).
// Pass 1: QK + exp + row sums (compute-only). Pass 2: attn write + PV.
// Double-buffered LDS staging with register prefetch, one barrier per tile.
// ---------------------------------------------------------------------------
__global__ __launch_bounds__(512) void attn_kernel(
    const __hip_bfloat16* __restrict__ qh, const __hip_bfloat16* __restrict__ kh,
    const __hip_bfloat16* __restrict__ vT, const unsigned long long* __restrict__ bits,
    float* __restrict__ attn, __hip_bfloat16* __restrict__ ctx)
{
    __shared__ __align__(16) short Ks[2][64][72];
    __shared__ __align__(16) short Vs[2][64][72];   // Vs[d][k]
    __shared__ __align__(16) short Ps[8][16][72];   // per-wave P tile
    const int t = threadIdx.x, lane = t & 63, w = t >> 6;

    // XCD grouping: 512 blocks, 8 XCDs -> XCD x gets 4 contiguous heads
    const int logical = (blockIdx.x & 7) * 64 + (blockIdx.x >> 3);
    const int qt = logical & 15;
    const int bh = logical >> 4;
    const int h = bh & (HH - 1);
    const int b = bh >> 4;
    const int q0w = qt * 128 + w * 16;            // this wave's 16 q-rows
    const size_t headbase = (size_t)bh * SS * DKV;
    const int lr = lane & 15;
    const int kb = (lane >> 4) * 8;
    const int Q4 = lane >> 4;
    const int rbase = Q4 * 4;

    const short* kbase = (const short*)kh + headbase;
    const short* vbase = (const short*)vT + (size_t)bh * DKV * SS;
    const unsigned long long* bitrow = bits + ((size_t)b * SS + q0w) * (SS / 64);

    // staging coords: each thread one short8 per tile per matrix
    const int srow = t >> 3, sc8 = (t & 7) * 8;
    const short* kstg = kbase + (size_t)srow * DKV + sc8;   // + kt*64*DKV
    const short* vstg = vbase + (size_t)srow * SS + sc8;    // + kt*64

    // Q fragments (resident)
    const short* qrp = (const short*)qh + headbase + (size_t)(q0w + lr) * DKV;
    const short8 aq0 = *(const short8*)(qrp + kb);
    const short8 aq1 = *(const short8*)(qrp + 32 + kb);

    float lsum[4] = {0.f, 0.f, 0.f, 0.f};

    // ---------------- pass 1: row sums (bits from L2) ----------------
    {
        short8 kreg = *(const short8*)(kstg);
        *(short8*)&Ks[0][srow][sc8] = kreg;
        __syncthreads();
        for (int kt = 0; kt < 32; ++kt) {
            const int cur = kt & 1;
            if (kt + 1 < 32)
                kreg = *(const short8*)(kstg + (size_t)(kt + 1) * 64 * DKV);
            f32x4 sc[4];
            #pragma unroll
            for (int fc = 0; fc < 4; ++fc) {
                short8 bk0 = *(const short8*)&Ks[cur][fc * 16 + lr][kb];
                short8 bk1 = *(const short8*)&Ks[cur][fc * 16 + lr][32 + kb];
                f32x4 s = {0.f, 0.f, 0.f, 0.f};
                s = MFMA16(aq0, bk0, s);
                s = MFMA16(aq1, bk1, s);
                sc[fc] = s;
            }
            unsigned long long mw[4];
            #pragma unroll
            for (int r = 0; r < 4; ++r)
                mw[r] = bitrow[(size_t)(rbase + r) * (SS / 64) + kt];
            #pragma unroll
            for (int fc = 0; fc < 4; ++fc)
                #pragma unroll
                for (int r = 0; r < 4; ++r) {
                    const bool masked = (mw[r] >> (fc * 16 + lr)) & 1ull;
                    lsum[r] += masked ? 0.f : __expf(sc[fc][r] * 0.125f);
                }
            if (kt + 1 < 32)
                *(short8*)&Ks[cur ^ 1][srow][sc8] = kreg;
            __syncthreads();
        }
    }
    #pragma unroll
    for (int r = 0; r < 4; r++) {
        float s = lsum[r];
        s += __shfl_xor(s, 1);
        s += __shfl_xor(s, 2);
        s += __shfl_xor(s, 4);
        s += __shfl_xor(s, 8);
        lsum[r] = s;
    }
    float linv[4];
    #pragma unroll
    for (int r = 0; r < 4; r++) linv[r] = 1.f / lsum[r];

    f32x4 cacc[4] = {};
    float* arow = attn + ((size_t)bh * SS + q0w) * SS;

    // ---------------- pass 2: attn write + context ----------------
    {
        short8 kreg = *(const short8*)(kstg);
        short8 vreg = *(const short8*)(vstg);
        *(short8*)&Ks[0][srow][sc8] = kreg;
        *(short8*)&Vs[0][srow][sc8] = vreg;
        __syncthreads();
        for (int kt = 0; kt < 32; ++kt) {
            const int cur = kt & 1;
            const int k0 = kt * 64;
            if (kt + 1 < 32) {
                kreg = *(const short8*)(kstg + (size_t)(kt + 1) * 64 * DKV);
                vreg = *(const short8*)(vstg + (size_t)(kt + 1) * 64);
            }
            f32x4 sc[4];
            #pragma unroll
            for (int fc = 0; fc < 4; ++fc) {
                short8 bk0 = *(const short8*)&Ks[cur][fc * 16 + lr][kb];
                short8 bk1 = *(const short8*)&Ks[cur][fc * 16 + lr][32 + kb];
                f32x4 s = {0.f, 0.f, 0.f, 0.f};
                s = MFMA16(aq0, bk0, s);
                s = MFMA16(aq1, bk1, s);
                sc[fc] = s;
            }
            unsigned long long mw[4];
            #pragma unroll
            for (int r = 0; r < 4; ++r)
                mw[r] = bitrow[(size_t)(rbase + r) * (SS / 64) + kt];
            #pragma unroll
            for (int fc = 0; fc < 4; ++fc)
                #pragma unroll
                for (int r = 0; r < 4; ++r) {
                    const bool masked = (mw[r] >> (fc * 16 + lr)) & 1ull;
                    const float p = masked ? 0.f : __expf(sc[fc][r] * 0.125f) * linv[r];
                    arow[(size_t)(rbase + r) * SS + k0 + fc * 16 + lr] = p;
                    Ps[w][rbase + r][fc * 16 + lr] = f2bf(p);
                }
            // wave-internal LDS dependency (lgkmcnt handled by compiler)
            short8 ap0 = *(const short8*)&Ps[w][lr][kb];
            short8 ap1 = *(const short8*)&Ps[w][lr][32 + kb];
            #pragma unroll
            for (int fd = 0; fd < 4; ++fd) {
                short8 bv0 = *(const short8*)&Vs[cur][fd * 16 + lr][kb];
                short8 bv1 = *(const short8*)&Vs[cur][fd * 16 + lr][32 + kb];
                cacc[fd] = MFMA16(ap0, bv0, cacc[fd]);
                cacc[fd] = MFMA16(ap1, bv1, cacc[fd]);
            }
            if (kt + 1 < 32) {
                *(short8*)&Ks[cur ^ 1][srow][sc8] = kreg;
                *(short8*)&Vs[cur ^ 1][srow][sc8] = vreg;
            }
            __syncthreads();
        }
    }

    #pragma unroll
    for (int fd = 0; fd < 4; ++fd)
        #pragma unroll
        for (int r = 0; r < 4; r++) {
            const int qrow = q0w + rbase + r;
            ctx[((size_t)b * SS + qrow) * DD + h * DKV + fd * 16 + lr] =
                __float2bfloat16(cacc[fd][r]);
        }
}

// ---------------------------------------------------------------------------
// LayerNorm in place on out[4096][1024], biased var, eps=1e-5
// ---------------------------------------------------------------------------
__global__ __launch_bounds__(256) void ln_kernel(
    float* __restrict__ io, const float* __restrict__ g, const float* __restrict__ bta)
{
    const int row = blockIdx.x;
    const int t = threadIdx.x;
    float* p = io + (size_t)row * DD;
    float4 x = *(float4*)(p + t * 4);
    float s  = x.x + x.y + x.z + x.w;
    float s2 = x.x * x.x + x.y * x.y + x.z * x.z + x.w * x.w;
    #pragma unroll
    for (int off = 32; off; off >>= 1) {
        s  += __shfl_xor(s, off);
        s2 += __shfl_xor(s2, off);
    }
    __shared__ float as_[4], bs_[4];
    const int w = t >> 6, l = t & 63;
    if (!l) { as_[w] = s; bs_[w] = s2; }
    __syncthreads();
    s  = as_[0] + as_[1] + as_[2] + as_[3];
    s2 = bs_[0] + bs_[1] + bs_[2] + bs_[3];
    const float mu  = s * (1.f / DD);
    const float var = s2 * (1.f / DD) - mu * mu;
    const float rs  = rsqrtf(var + 1e-5f);
    float4 gv = *(const float4*)(g + t * 4);
    float4 bv = *(const float4*)(bta + t * 4);
    float4 o;
    o.x = (x.x - mu) * rs * gv.x + bv.x;
    o.y = (x.y - mu) * rs * gv.y + bv.y;
    o.z = (x.z - mu) * rs * gv.z + bv.z;
    o.w = (x.w - mu) * rs * gv.w + bv.w;
    *(float4*)(p + t * 4) = o;
}

// ---------------------------------------------------------------------------
extern "C" void kernel_launch(void* const* d_in, const int* in_sizes, int n_in,
                              void* d_out, int out_size, void* d_ws, size_t ws_size,
                              hipStream_t stream)
{
    (void)in_sizes; (void)n_in; (void)out_size; (void)ws_size;
    const float* q     = (const float*)d_in[0];
    const float* k     = (const float*)d_in[1];
    const float* v     = (const float*)d_in[2];
    const int*   mask  = (const int*)d_in[3];
    const float* wq    = (const float*)d_in[4];
    const float* bq    = (const float*)d_in[5];
    const float* wk    = (const float*)d_in[6];
    const float* bk    = (const float*)d_in[7];
    const float* wv    = (const float*)d_in[8];
    const float* bv    = (const float*)d_in[9];
    const float* wo    = (const float*)d_in[10];
    const float* bo    = (const float*)d_in[11];
    const float* gamma = (const float*)d_in[12];
    const float* beta  = (const float*)d_in[13];

    float* out  = (float*)d_out;                    // [B,S,D]
    float* attn = out + (size_t)BB * SS * DD;       // [B,H,S,S]

    const size_t hsz = (size_t)BB * HH * SS * DKV;  // 4,194,304
    __hip_bfloat16* qhp = (__hip_bfloat16*)d_ws;
    __hip_bfloat16* khp = qhp + hsz;
    __hip_bfloat16* vTp = khp + hsz;                // vT[b][h][d][s]
    __hip_bfloat16* ctx = vTp + hsz;
    unsigned long long* bits = (unsigned long long*)(ctx + hsz);  // 1 MB

    dim3 gg(32, 8, 4);  // z=0: mask pack; z=1..3: q/k/v projections
    proj3_kernel<<<gg, 256, 0, stream>>>(q, k, v, wq, wk, wv, bq, bk, bv,
                                         qhp, khp, vTp, mask, bits);
    attn_kernel<<<BB * HH * 16, 512, 0, stream>>>(qhp, khp, vTp, bits, attn, ctx);
    dim3 go(32, 8);
    outproj_kernel<<<go, 256, 0, stream>>>(ctx, wo, bo, q, out);
    ln_kernel<<<BB * SS, 256, 0, stream>>>(out, gamma, beta);
}